// Round 8
// baseline (50.161 us; speedup 1.0000x reference)
//
#include <hip/hip_runtime.h>

// x: (64, 64, 128, 128) f32; weight: (64, 128, 3, 3) f32; bias: (128,) f32
// out: (64, 128, 1, 1) f32
// out[b][o] = 2*bias[o] + (2/65536) * sum_c [ s_full*cf + s_top*ct + s_left*cl + s_corner*w00 ]
//
// R7 structure (48.7us): single streaming kernel, one block per (b,c) image,
// relaxed hw fp32 atomicAdd epilogue (NO acq_rel — that collapsed BW in R3/R4).
// R8 delta: nontemporal x loads (nt bit) — single-use stream shouldn't fill L2;
// also keeps the 288KB weight table L2-resident for every block's epilogue.

typedef float fvec4 __attribute__((ext_vector_type(4)));

__global__ __launch_bounds__(256) void fused_stats_kernel(const float* __restrict__ x,
                                                          const float* __restrict__ weight,
                                                          const float* __restrict__ bias,
                                                          float* __restrict__ out) {
    const int bc = blockIdx.x;            // b*64 + c
    const int b = bc >> 6, c = bc & 63;
    const int tid = threadIdx.x;
    const int wave = tid >> 6, lane = tid & 63;
    const fvec4* img = reinterpret_cast<const fvec4*>(x) + (size_t)bc * 4096;

    // each wave streams a contiguous 16 KiB quarter of the image
    float s_full = 0.f, s_top = 0.f, s_leftraw = 0.f, s_corner = 0.f;
    #pragma unroll
    for (int it = 0; it < 16; ++it) {
        const int idx = wave * 1024 + it * 64 + lane;   // float4 index
        fvec4 v = __builtin_nontemporal_load(img + idx);
        const float s4 = (v.x + v.y) + (v.z + v.w);
        s_full += s4;
        if (idx < 32) s_top += s4;        // row 0 = float4 indices 0..31
        s_leftraw += v.x;                 // col-0 candidate (lanes with idx%32==0)
        if (idx == 0) s_corner = v.x;
    }
    float s_left = ((lane & 31) == 0) ? s_leftraw : 0.f;

    #pragma unroll
    for (int off = 32; off > 0; off >>= 1) {
        s_full   += __shfl_down(s_full, off);
        s_top    += __shfl_down(s_top, off);
        s_left   += __shfl_down(s_left, off);
        s_corner += __shfl_down(s_corner, off);
    }

    __shared__ float red[4][4];
    __shared__ float st[4];
    if (lane == 0) {
        red[wave][0] = s_full;  red[wave][1] = s_top;
        red[wave][2] = s_left;  red[wave][3] = s_corner;
    }
    __syncthreads();
    if (tid < 4)
        st[tid] = (red[0][tid] + red[1][tid]) + (red[2][tid] + red[3][tid]);
    __syncthreads();

    // fold this (b,c) block's contribution into out[b][*]
    if (tid < 128) {
        const int o = tid;
        const float* w = weight + ((size_t)c * 128 + o) * 9;   // L2-hot (288 KB total)
        const float w0=w[0], w1=w[1], w2=w[2], w3=w[3], w4=w[4],
                    w5=w[5], w6=w[6], w7=w[7], w8=w[8];
        const float cf = ((w0 + w1) + (w2 + w3)) + ((w4 + w5) + (w6 + w7)) + w8;
        const float ct = -((w0 + w1) + w2);
        const float cl = -((w0 + w3) + w6);
        float contrib = (st[0]*cf + st[1]*ct + st[2]*cl + st[3]*w0) * (2.0f / 65536.0f);
        if (c == 0) contrib += 2.0f * bias[o];
        unsafeAtomicAdd(&out[b * 128 + o], contrib);   // relaxed hw fp32 atomic
    }
}

extern "C" void kernel_launch(void* const* d_in, const int* in_sizes, int n_in,
                              void* d_out, int out_size, void* d_ws, size_t ws_size,
                              hipStream_t stream) {
    const float* x      = (const float*)d_in[0];
    const float* weight = (const float*)d_in[1];
    const float* bias   = (const float*)d_in[2];
    float* out = (float*)d_out;

    (void)hipMemsetAsync(out, 0, (size_t)out_size * sizeof(float), stream); // graph memset node
    fused_stats_kernel<<<4096, 256, 0, stream>>>(x, weight, bias, out);
}

// Round 9
// 48.751 us; speedup vs baseline: 1.0289x; 1.0289x over previous
//
#include <hip/hip_runtime.h>

// x: (64, 64, 128, 128) f32; weight: (64, 128, 3, 3) f32; bias: (128,) f32
// out: (64, 128, 1, 1) f32
// out[b][o] = 2*bias[o] + (2/65536) * sum_c [ s_full*cf + s_top*ct + s_left*cl + s_corner*w00 ]
//
// R7 structure (48.7us proven): relaxed hw fp32 atomicAdd epilogue (no acq_rel
// — that collapsed BW in R3/R4), no nontemporal (R8: NT regressed to 50.2us).
// R9 delta: persistent grid — 2048 blocks (8/CU, full 32-wave occupancy), each
// block streams 2 consecutive images; single dispatch round, one ramp/tail.

typedef float fvec4 __attribute__((ext_vector_type(4)));

__global__ __launch_bounds__(256) void fused_stats_kernel(const float* __restrict__ x,
                                                          const float* __restrict__ weight,
                                                          const float* __restrict__ bias,
                                                          float* __restrict__ out) {
    const int tid = threadIdx.x;
    const int wave = tid >> 6, lane = tid & 63;

    __shared__ float red[4][4];
    __shared__ float st[4];

    #pragma unroll
    for (int i = 0; i < 2; ++i) {
        const int bc = blockIdx.x * 2 + i;        // b*64 + c
        const int b = bc >> 6, c = bc & 63;
        const fvec4* img = reinterpret_cast<const fvec4*>(x) + (size_t)bc * 4096;

        // each wave streams a contiguous 16 KiB quarter of the image
        float s_full = 0.f, s_top = 0.f, s_leftraw = 0.f, s_corner = 0.f;
        #pragma unroll
        for (int it = 0; it < 16; ++it) {
            const int idx = wave * 1024 + it * 64 + lane;   // float4 index
            fvec4 v = img[idx];
            const float s4 = (v.x + v.y) + (v.z + v.w);
            s_full += s4;
            if (idx < 32) s_top += s4;        // row 0 = float4 indices 0..31
            s_leftraw += v.x;                 // col-0 candidate (lanes idx%32==0)
            if (idx == 0) s_corner = v.x;
        }
        float s_left = ((lane & 31) == 0) ? s_leftraw : 0.f;

        #pragma unroll
        for (int off = 32; off > 0; off >>= 1) {
            s_full   += __shfl_down(s_full, off);
            s_top    += __shfl_down(s_top, off);
            s_left   += __shfl_down(s_left, off);
            s_corner += __shfl_down(s_corner, off);
        }

        if (lane == 0) {
            red[wave][0] = s_full;  red[wave][1] = s_top;
            red[wave][2] = s_left;  red[wave][3] = s_corner;
        }
        __syncthreads();
        if (tid < 4)
            st[tid] = (red[0][tid] + red[1][tid]) + (red[2][tid] + red[3][tid]);
        __syncthreads();

        // fold this (b,c) image's contribution into out[b][*]
        if (tid < 128) {
            const int o = tid;
            const float* w = weight + ((size_t)c * 128 + o) * 9;   // L2-hot
            const float w0=w[0], w1=w[1], w2=w[2], w3=w[3], w4=w[4],
                        w5=w[5], w6=w[6], w7=w[7], w8=w[8];
            const float cf = ((w0 + w1) + (w2 + w3)) + ((w4 + w5) + (w6 + w7)) + w8;
            const float ct = -((w0 + w1) + w2);
            const float cl = -((w0 + w3) + w6);
            float contrib = (st[0]*cf + st[1]*ct + st[2]*cl + st[3]*w0) * (2.0f / 65536.0f);
            if (c == 0) contrib += 2.0f * bias[o];
            unsafeAtomicAdd(&out[b * 128 + o], contrib);   // relaxed hw fp32 atomic
        }
        __syncthreads();   // red[]/st[] reused by next image
    }
}

extern "C" void kernel_launch(void* const* d_in, const int* in_sizes, int n_in,
                              void* d_out, int out_size, void* d_ws, size_t ws_size,
                              hipStream_t stream) {
    const float* x      = (const float*)d_in[0];
    const float* weight = (const float*)d_in[1];
    const float* bias   = (const float*)d_in[2];
    float* out = (float*)d_out;

    (void)hipMemsetAsync(out, 0, (size_t)out_size * sizeof(float), stream); // graph memset node
    fused_stats_kernel<<<2048, 256, 0, stream>>>(x, weight, bias, out);
}